// Round 9
// baseline (459.624 us; speedup 1.0000x reference)
//
#include <hip/hip_runtime.h>
#include <stdint.h>

#define EPSV 1e-5f

// c8-chunked activation layout: elem = cc*278784 + ((b*66+y)*66+x)*8 + (c&7)
#define CPLANE 278784   // 8*66*66*8 elems per channel-chunk plane

using floatx4 = __attribute__((ext_vector_type(4))) float;
using short8  = __attribute__((ext_vector_type(8))) short;

// async global->LDS 16B DMA: data lands at ldsbase + lane*16
#define GLD(gp, lp) __builtin_amdgcn_global_load_lds( \
    (const __attribute__((address_space(1))) void*)(gp), \
    (__attribute__((address_space(3))) void*)(lp), 16, 0, 0)

__device__ __forceinline__ unsigned short f2bf(float f) {
  union { float f; unsigned int u; } x; x.f = f;
  unsigned int r = x.u + 0x7fffu + ((x.u >> 16) & 1u);  // RNE
  return (unsigned short)(r >> 16);
}

// ---------------------------------------------------------------------------
// Zero the halo border of both padded c8 buffers (2.13 MB each).
// ---------------------------------------------------------------------------
__global__ __launch_bounds__(256) void border_zero_kernel(
    unsigned short* __restrict__ Xp0, unsigned short* __restrict__ Xp1) {
  int idx = blockIdx.x * 256 + threadIdx.x;   // 520*256 = 133120 = 8*64*260
  int k = idx % 260;
  int rest = idx / 260;
  int cc = rest & 63;
  int b = rest >> 6;
  int py, px;
  if (k < 66)       { py = 0;  px = k; }
  else if (k < 132) { py = 65; px = k - 66; }
  else { int k2 = k - 132; py = 1 + (k2 >> 1); px = (k2 & 1) ? 65 : 0; }
  int off = cc * CPLANE + ((b * 66 + py) * 66 + px) * 8;
  short8 z = {};
  *(short8*)(Xp0 + off) = z;
  *(short8*)(Xp1 + off) = z;
}

// ---------------------------------------------------------------------------
// Upsample (align-corners bilinear 32->64) + alpha*xm fuse -> bf16 c8 layout.
// ---------------------------------------------------------------------------
__global__ __launch_bounds__(256) void fuse_upsample_kernel(
    const float* __restrict__ xt, const float* __restrict__ xm,
    const float* __restrict__ alpha, unsigned short* __restrict__ Xp) {
  __shared__ float sm[32 * 66];        // xm tile [c][x], pad 66
  __shared__ float st[2 * 32 * 34];    // xt rows [h][c][x0..31], pad 34

  const int tid = threadIdx.x;
  const int ct = blockIdx.x & 15;          // channel tile (32 ch)
  const int y  = (blockIdx.x >> 4) & 63;
  const int b  = blockIdx.x >> 10;
  const int c0 = ct * 32;

  const float fy = y * (31.0f / 63.0f);
  const int y0 = (int)fy;
  const float wy = fy - (float)y0;
  const int y1 = min(y0 + 1, 31);

  // phase 1: xm tile, lane = x (coalesced 256B rows)
  {
    const int cb = (tid >> 6) * 8;
    const int xi = tid & 63;
#pragma unroll
    for (int j = 0; j < 8; ++j) {
      int c = cb + j;
      sm[c * 66 + xi] = xm[(((b << 9) + c0 + c) << 12) + (y << 6) + xi];
    }
  }
  // phase 2: xt rows y0,y1 (32 x-contiguous floats per (h,c) -> coalesced)
#pragma unroll
  for (int j = 0; j < 8; ++j) {
    int idx = j * 256 + tid;
    int xi = idx & 31, cc = (idx >> 5) & 31, h = idx >> 10;
    int yr = h ? y1 : y0;
    st[h * 1088 + cc * 34 + xi] =
        xt[(((b << 9) + c0 + cc) << 10) + (yr << 5) + xi];
  }
  __syncthreads();

  // phase 3: interpolate + fuse, write one c8 chunk per thread
  const float a = alpha[0];
  const int xo = tid & 63;
  const int cl = tid >> 6;             // local cchunk 0..3
  const float fx = xo * (31.0f / 63.0f);
  const int x0 = (int)fx;
  const float wx = fx - (float)x0;
  const int x1 = min(x0 + 1, 31);
  short8 ov;
#pragma unroll
  for (int j = 0; j < 8; ++j) {
    int c = cl * 8 + j;
    float t0 = st[c * 34 + x0], t1 = st[c * 34 + x1];
    float u0 = st[1088 + c * 34 + x0], u1 = st[1088 + c * 34 + x1];
    float top = t0 * (1.0f - wx) + t1 * wx;
    float bot = u0 * (1.0f - wx) + u1 * wx;
    float up = top * (1.0f - wy) + bot * wy;
    float val = up + a * sm[c * 66 + xo];
    ov[j] = (short)f2bf(val);
  }
  *(short8*)(Xp + ((c0 >> 3) + cl) * CPLANE +
             ((b * 66 + y + 1) * 66 + xo + 1) * 8) = ov;
}

// ---------------------------------------------------------------------------
// Repack weights OIHW fp32 -> [tap][cinchunk][cout][8] bf16 via LDS transpose.
// ---------------------------------------------------------------------------
template <int COUT>
__global__ __launch_bounds__(256) void prep_w_kernel(
    const float* __restrict__ w, unsigned short* __restrict__ Wg) {
  __shared__ unsigned short l[4608];   // [tap][cin]
  const int o = blockIdx.x, t = threadIdx.x;
  const float* src = w + o * 4608;
#pragma unroll
  for (int j = 0; j < 18; ++j) {
    int idx = j * 256 + t;             // = i*9 + tap
    l[(idx % 9) * 512 + idx / 9] = f2bf(src[idx]);
  }
  __syncthreads();
#pragma unroll
  for (int tap = 0; tap < 9; ++tap) {
    int cc = t >> 2;
    int off = ((tap * 64 + cc) * COUT + o) * 8 + ((2 * t) & 7);
    *(unsigned int*)(Wg + off) = *(const unsigned int*)(l + (tap << 9) + 2 * t);
  }
}

// ---------------------------------------------------------------------------
// FAT-WAVE implicit-GEMM 3x3 conv + BN + ReLU (conv0), counted-vmcnt pipeline.
// Block 256px x 256cout, 8 waves (2x4), wave 128px x 64cout, acc[8][4].
// 1 block/CU -> a per-tap __syncthreads (vmcnt(0) drain) would stall ALL
// waves on the freshest B DMA (round-7: MfmaUtil 53%). Instead: B is
// triple-buffered (slot = tap%3, static after unroll since 9%3==0); each
// tap issues tap+2's prefetch, computes tap, then raw `s_waitcnt vmcnt(4)`
// (tap+1's 4 GLDs landed; tap+2's 4 remain in flight ACROSS the barrier)
// followed by raw s_barrier. Full vmcnt(0) drains only at cg boundaries
// (A restage) and in the cg=7 tail (no prefetch follows there).
//
// Safety argument (audited r8/r9):
//  * vmcnt accounting per wave: 4 -> 8 -> wait-to-4 each tap, so the OLDEST
//    4 ops (tap+1's B slice owned by this wave) are complete before the
//    barrier that publishes them; every wave certifies its own kc-slice.
//  * Slot (t+2)%3 == (t-1)%3 is rewritten only after the barrier ending
//    tap t-1, by which point all waves' ds_reads of it have drained
//    (lgkmcnt waits precede the consuming MFMAs, which precede the barrier).
//  * All barriers sit in wave-uniform control flow; counts match.
// LDS = 50816 + 3*32896 = 149504 B <= 160K.
// ---------------------------------------------------------------------------
template <int COUT, bool FINAL>
__global__ __launch_bounds__(512, 2) void conv3x3_fat_kernel(
    const unsigned short* __restrict__ Xp, const unsigned short* __restrict__ Wg,
    const float* __restrict__ gamma, const float* __restrict__ beta,
    const float* __restrict__ mean, const float* __restrict__ var,
    unsigned short* __restrict__ OutPad, float* __restrict__ OutF) {
  constexpr int NCT = COUT / 256;          // ctile count
  constexpr int NWG = 128 * NCT;           // 128 ptiles (256 px each)
  constexpr int QPX = NWG / 8;             // blocks per XCD
  constexpr int AKS = 3176;                // A kc stride shorts (6*528 + 8)
  constexpr int BKS = 2056;                // B kc stride shorts (256*8 + 8)
  __shared__ unsigned short Abuf[8 * AKS];     // 50816 B: [kc][6 rows][528]
  __shared__ unsigned short Bbuf[3][8 * BKS];  // 3 x 32896 B ring

  const int tid = threadIdx.x;
  const int w = tid >> 6;              // wave 0..7
  const int lane = tid & 63;
  const int wm = w >> 2;               // 0..1 : 128-px half (2 out rows)
  const int wn = w & 3;                // 0..3 : 64-cout quarter
  const int fi = lane & 15;
  const int kc4 = lane >> 4;           // 0..3

  // ---- XCD swizzle, ctile-major (each XCD covers one ctile slice)
  const int bid = (int)blockIdx.x;
  const int logical = (bid & 7) * QPX + (bid >> 3);
  const int ptile = logical & 127;
  const int ctile = logical >> 7;
  const int p0 = ptile * 256;          // 4 consecutive out rows of one batch
  const int pb = p0 >> 12;             // batch (16 ptiles/batch, no cross)
  const int y0 = (p0 >> 6) & 63;       // first out row
  const int arowg = ((pb * 66 + y0) * 66) * 8;  // padded rows y0..y0+5

  floatx4 acc[8][4] = {};

  // ---- A staging: wave w owns kchunk w; 6 rows, 1056 B each (overlap trick)
  auto stageA = [&](int cg) {
    const unsigned short* g = Xp + (cg * 8 + w) * CPLANE + arowg + lane * 8;
    unsigned short* d = Abuf + w * AKS;
#pragma unroll
    for (int rr = 0; rr < 6; ++rr) {
      GLD(g + rr * 528,      d + rr * 528);        // shorts [0,512)
      GLD(g + rr * 528 + 16, d + rr * 528 + 16);   // shorts [16,528)
    }
  };
  // ---- B staging: wave w owns kchunk w; 256 couts = 4 x 1 KiB chunks
  auto stageB = [&](int tap, int cg, unsigned short* dst) {
    const unsigned short* g =
        Wg + ((tap * 64 + cg * 8 + w) * COUT + ctile * 256) * 8 + lane * 8;
    unsigned short* d = dst + w * BKS;
#pragma unroll
    for (int ch = 0; ch < 4; ++ch) GLD(g + ch * 512, d + ch * 512);
  };
  auto compute = [&](const unsigned short* Bsel, int dy, int dx) {
#pragma unroll
    for (int t = 0; t < 2; ++t) {
      const unsigned short* ab = Abuf + (kc4 + 4 * t) * AKS;
      short8 af[8];
#pragma unroll
      for (int mi = 0; mi < 8; ++mi)
        af[mi] = *(const short8*)(ab + (wm * 2 + (mi >> 2) + 1 + dy) * 528 +
                                  ((mi & 3) * 16 + fi + 1 + dx) * 8);
      const unsigned short* bb =
          Bsel + (kc4 + 4 * t) * BKS + (wn * 64 + fi) * 8;
      short8 bfr[4];
#pragma unroll
      for (int ni = 0; ni < 4; ++ni)
        bfr[ni] = *(const short8*)(bb + ni * 128);
#pragma unroll
      for (int mi = 0; mi < 8; ++mi)
#pragma unroll
        for (int ni = 0; ni < 4; ++ni)
          acc[mi][ni] = __builtin_amdgcn_mfma_f32_16x16x32_bf16(
              af[mi], bfr[ni], acc[mi][ni], 0, 0, 0);
    }
  };

  // ---- prologue: A(cg0) + B steps 0,1 staged and drained
  stageA(0);
  stageB(0, 0, Bbuf[0]);
  stageB(1, 0, Bbuf[1]);
  asm volatile("s_waitcnt vmcnt(0)" ::: "memory");
  __builtin_amdgcn_s_barrier();

  // ---- main loop, cg 0..6: counted-vmcnt barriers, loads fly across them
  for (int cg = 0; cg < 7; ++cg) {
#pragma unroll
    for (int tap = 0; tap < 9; ++tap) {
      if (tap < 7) stageB(tap + 2, cg,     Bbuf[(tap + 2) % 3]);
      else         stageB(tap - 7, cg + 1, Bbuf[(tap + 2) % 3]);
      compute(Bbuf[tap % 3], tap / 3 - 1, tap % 3 - 1);
      asm volatile("s_waitcnt vmcnt(4)" ::: "memory");  // tap+1's B landed
      __builtin_amdgcn_s_barrier();
      if (tap == 8) {
        stageA(cg + 1);     // A(cg) reads done by all waves (barrier above)
        asm volatile("s_waitcnt vmcnt(0)" ::: "memory");
        __builtin_amdgcn_s_barrier();
      }
    }
  }
  // ---- tail cg = 7: no further prefetch -> full drains (cheap, 9 of 72)
#pragma unroll
  for (int tap = 0; tap < 9; ++tap) {
    if (tap < 7) stageB(tap + 2, 7, Bbuf[(tap + 2) % 3]);
    compute(Bbuf[tap % 3], tap / 3 - 1, tap % 3 - 1);
    __syncthreads();
  }

  // ---- epilogue: BN + ReLU
  // C/D layout: col = lane&15 (=cout), row = (lane>>4)*4 + reg (=pixel)
#pragma unroll
  for (int ni = 0; ni < 4; ++ni) {
    const int co = ctile * 256 + wn * 64 + ni * 16 + fi;
    const float sc = gamma[co] / sqrtf(var[co] + EPSV);
    const float sh2 = beta[co] - mean[co] * sc;
#pragma unroll
    for (int mi = 0; mi < 8; ++mi) {
      const int p = p0 + wm * 128 + mi * 16 + kc4 * 4;  // 4 consecutive px
      const int pbb = p >> 12;
      const int prem = p & 4095;
      if constexpr (FINAL) {
        floatx4 o;
#pragma unroll
        for (int r = 0; r < 4; ++r) o[r] = fmaxf(acc[mi][ni][r] * sc + sh2, 0.0f);
        *(floatx4*)(OutF + ((pbb * COUT + co) << 12) + prem) = o;  // NCHW fp32
      } else {
        const int py = prem >> 6, px = prem & 63;
        unsigned short* dst = OutPad + (co >> 3) * CPLANE +
            ((pbb * 66 + py + 1) * 66 + px + 1) * 8 + (co & 7);
#pragma unroll
        for (int r = 0; r < 4; ++r)
          dst[r * 8] = f2bf(fmaxf(acc[mi][ni][r] * sc + sh2, 0.0f));
      }
    }
  }
}

// ---------------------------------------------------------------------------
// Original implicit-GEMM conv (kept for conv1: COUT=256, CTILE=128,
// 2 blocks/CU). XCD-aware ctile-major swizzle, compile-time grid.
// ---------------------------------------------------------------------------
template <int COUT, int CTILE, bool FINAL>
__global__ __launch_bounds__(256) void conv3x3_kernel(
    const unsigned short* __restrict__ Xp, const unsigned short* __restrict__ Wg,
    const float* __restrict__ gamma, const float* __restrict__ beta,
    const float* __restrict__ mean, const float* __restrict__ var,
    unsigned short* __restrict__ OutPad, float* __restrict__ OutF) {
  constexpr int NCT = COUT / CTILE;
  constexpr int NI  = CTILE / 32;          // n-subtiles per wave
  constexpr int NWG = 256 * NCT;           // launched grid size (exact)
  constexpr int QPX = NWG / 8;             // blocks per XCD
  __shared__ unsigned short Abuf[16896];   // [kc 8][row 4][x 66][8] = 33 KiB
  __shared__ unsigned short Bbuf0[CTILE * 64];  // [kc 8][CTILE][8]
  __shared__ unsigned short Bbuf1[CTILE * 64];

  const int tid = threadIdx.x;
  const int bid = (int)blockIdx.x;
  const int logical = (bid & 7) * QPX + (bid >> 3);
  const int ptile = logical & 255;         // 256 ptiles (32768 px / 128)
  const int ctile = logical >> 8;
  const int p0 = ptile * 128;          // 2 consecutive y-rows of one batch
  const int w = tid >> 6;
  const int lane = tid & 63;

  const int pb = p0 >> 12;             // batch
  const int yb = (p0 >> 6) & 63;       // first input padded row (dy=-1)
  const int arowg = ((pb * 66 + yb) * 66) * 8;   // global elem offset of row 0

  const int fi = lane & 15;
  const int kc = lane >> 4;
  const int wm = w >> 1, wn = w & 1;
  const int aLane = kc * 2112 + (wm + 1) * 528 + (fi + 1) * 8;
  const int bLane = kc * CTILE * 8 + (wn * (CTILE / 2) + fi) * 8;

  floatx4 acc[4][NI] = {};

  auto stageA = [&](int cg) {
#pragma unroll
    for (int kk = 0; kk < 2; ++kk) {
      const int kc2 = 2 * w + kk;
      const unsigned short* g = Xp + (cg * 8 + kc2) * CPLANE + arowg + lane * 8;
      unsigned short* d = Abuf + kc2 * 2112;
#pragma unroll
      for (int rr = 0; rr < 4; ++rr) {
        GLD(g + rr * 528,      d + rr * 528);
        GLD(g + rr * 528 + 16, d + rr * 528 + 16);
      }
    }
  };
  auto stageB = [&](int tap, int cg, unsigned short* dst) {
#pragma unroll
    for (int kk = 0; kk < 2; ++kk) {
      const int kc2 = 2 * w + kk;
      const unsigned short* g =
          Wg + ((tap * 64 + cg * 8 + kc2) * COUT + ctile * CTILE + lane) * 8;
#pragma unroll
      for (int half = 0; half < CTILE / 64; ++half)
        GLD(g + half * 64 * 8, dst + (kc2 * CTILE + half * 64) * 8);
    }
  };
  auto compute = [&](const unsigned short* Bsel, int dy, int dx) {
#pragma unroll
    for (int t = 0; t < 2; ++t) {
      short8 af[4];
#pragma unroll
      for (int mi = 0; mi < 4; ++mi)
        af[mi] = *(const short8*)(Abuf + aLane + t * 8448 + dy * 528 +
                                  (mi * 16 + dx) * 8);
      short8 bfr[NI];
#pragma unroll
      for (int ni = 0; ni < NI; ++ni)
        bfr[ni] = *(const short8*)(Bsel + bLane + t * CTILE * 32 + ni * 128);
#pragma unroll
      for (int mi = 0; mi < 4; ++mi)
#pragma unroll
        for (int ni = 0; ni < NI; ++ni)
          acc[mi][ni] = __builtin_amdgcn_mfma_f32_16x16x32_bf16(
              af[mi], bfr[ni], acc[mi][ni], 0, 0, 0);
    }
  };

  int buf = 0;
  stageA(0);
  stageB(0, 0, Bbuf0);
  __syncthreads();
  for (int cg = 0; cg < 8; ++cg) {
#pragma unroll
    for (int tap = 0; tap < 9; ++tap) {
      unsigned short* cur = buf ? Bbuf1 : Bbuf0;
      unsigned short* nxt = buf ? Bbuf0 : Bbuf1;
      if (tap < 8)      stageB(tap + 1, cg, nxt);
      else if (cg < 7)  stageB(0, cg + 1, nxt);
      compute(cur, tap / 3 - 1, tap % 3 - 1);
      __syncthreads();
      buf ^= 1;
    }
    if (cg < 7) {
      stageA(cg + 1);
      __syncthreads();
    }
  }

#pragma unroll
  for (int ni = 0; ni < NI; ++ni) {
    const int co = ctile * CTILE + wn * (CTILE / 2) + ni * 16 + fi;
    const float sc = gamma[co] / sqrtf(var[co] + EPSV);
    const float sh2 = beta[co] - mean[co] * sc;
#pragma unroll
    for (int mi = 0; mi < 4; ++mi) {
      const int p = p0 + wm * 64 + mi * 16 + kc * 4;
      const int pbb = p >> 12;
      const int prem = p & 4095;
      if constexpr (FINAL) {
        floatx4 o;
#pragma unroll
        for (int r = 0; r < 4; ++r) o[r] = fmaxf(acc[mi][ni][r] * sc + sh2, 0.0f);
        *(floatx4*)(OutF + ((pbb * COUT + co) << 12) + prem) = o;
      } else {
        const int py = prem >> 6, px = prem & 63;
        unsigned short* dst = OutPad + (co >> 3) * CPLANE +
            ((pbb * 66 + py + 1) * 66 + px + 1) * 8 + (co & 7);
#pragma unroll
        for (int r = 0; r < 4; ++r)
          dst[r * 8] = f2bf(fmaxf(acc[mi][ni][r] * sc + sh2, 0.0f));
      }
    }
  }
}

// ---------------------------------------------------------------------------
// workspace layout (bytes):
//   Xp0 : 0          .. 35684352   (64cc * 8*66*66 * 8 bf16)
//   Xp1 : 35684352   .. 71368704
//   Wg0 : 71368704   .. 76087296   (9*64*512*8 bf16)
//   Wg1 : 76087296   .. 78446592   (9*64*256*8 bf16)
// ---------------------------------------------------------------------------
extern "C" void kernel_launch(void* const* d_in, const int* in_sizes, int n_in,
                              void* d_out, int out_size, void* d_ws, size_t ws_size,
                              hipStream_t stream) {
  const float* xt    = (const float*)d_in[0];
  const float* xm    = (const float*)d_in[1];
  const float* alpha = (const float*)d_in[3];
  const float* w0    = (const float*)d_in[4];
  const float* g0    = (const float*)d_in[5];
  const float* b0    = (const float*)d_in[6];
  const float* m0    = (const float*)d_in[7];
  const float* v0    = (const float*)d_in[8];
  const float* w1    = (const float*)d_in[9];
  const float* g1    = (const float*)d_in[10];
  const float* b1    = (const float*)d_in[11];
  const float* m1    = (const float*)d_in[12];
  const float* v1    = (const float*)d_in[13];
  float* out = (float*)d_out;

  char* ws = (char*)d_ws;
  unsigned short* Xp0 = (unsigned short*)(ws);
  unsigned short* Xp1 = (unsigned short*)(ws + 35684352);
  unsigned short* Wg0 = (unsigned short*)(ws + 2 * 35684352);
  unsigned short* Wg1 = (unsigned short*)(ws + 2 * 35684352 + 4718592);

  border_zero_kernel<<<520, 256, 0, stream>>>(Xp0, Xp1);
  prep_w_kernel<512><<<512, 256, 0, stream>>>(w0, Wg0);
  prep_w_kernel<256><<<256, 256, 0, stream>>>(w1, Wg1);
  fuse_upsample_kernel<<<8192, 256, 0, stream>>>(xt, xm, alpha, Xp0);
  conv3x3_fat_kernel<512, false><<<256, 512, 0, stream>>>(Xp0, Wg0, g0, b0, m0, v0, Xp1, nullptr);
  conv3x3_kernel<256, 128, true><<<512, 256, 0, stream>>>(Xp1, Wg1, g1, b1, m1, v1, nullptr, out);
}